// Round 3
// baseline (1450.500 us; speedup 1.0000x reference)
//
#include <hip/hip_runtime.h>

#define NI 8
#define NH 64
#define NO 8
#define NB 256
#define NT 2048

// tanh(s) = 1 - 2/(exp(2s)+1); safe at +-inf
__device__ __forceinline__ float tanh_fast(float s) {
    float e = __expf(2.0f * s);
    return fmaf(-2.0f, __builtin_amdgcn_rcpf(e + 1.0f), 1.0f);
}

// ONE wave per batch element, ZERO barriers. Cross-lane broadcast via LDS,
// relying on in-order LDS completion within a single wave (no __syncthreads).
// Per step:
//   phase 1: s0 = carry(Whh0@h0[t-1]) + Wih0@x[t] + b0 ; h0[t]=tanh(s0) -> LDS
//   phase 2: Whh1@h1[t-1] (bcast read h1s) + FC for t-1 from same h1[t-1]
//   phase 3: bcast read h0[t]; Wih1 dot (this step) AND Whh0 dot (next carry)
//   phase 4: h1[t] = tanh(...) -> LDS
// The write->read round trip of h0s (phase1->phase3) is hidden under phase 2's
// 64 independent FMAs; tanh latencies are hidden the same way.
__global__ void __launch_bounds__(64, 1) rnn_wave(
    const float* __restrict__ x,
    const float* __restrict__ W_ih0, const float* __restrict__ W_hh0,
    const float* __restrict__ b_ih0, const float* __restrict__ b_hh0,
    const float* __restrict__ W_ih1, const float* __restrict__ W_hh1,
    const float* __restrict__ b_ih1, const float* __restrict__ b_hh1,
    const float* __restrict__ W_fc,  const float* __restrict__ b_fc,
    float* __restrict__ out)
{
    const int b    = blockIdx.x;
    const int lane = threadIdx.x;

    // ---- per-lane weight rows (lane j = neuron j) ----
    float wih0[NI];
    #pragma unroll
    for (int i = 0; i < NI; ++i) wih0[i] = W_ih0[lane*NI + i];
    float whh0[NH], wih1[NH], whh1[NH];
    #pragma unroll
    for (int k = 0; k < NH; ++k) whh0[k] = W_hh0[lane*NH + k];
    #pragma unroll
    for (int k = 0; k < NH; ++k) wih1[k] = W_ih1[lane*NH + k];
    #pragma unroll
    for (int k = 0; k < NH; ++k) whh1[k] = W_hh1[lane*NH + k];
    const float bias0 = b_ih0[lane] + b_hh0[lane];
    const float bias1 = b_ih1[lane] + b_hh1[lane];

    // FC slice: lane = (kg, o)
    const int o  = lane & 7;
    const int kg = lane >> 3;
    float wfc[8];
    #pragma unroll
    for (int m = 0; m < 8; ++m) wfc[m] = W_fc[o*NH + kg*8 + m];
    const float bfc = b_fc[o];

    __shared__ float xs[64*NI];   // one x chunk (64 timesteps)
    __shared__ float h0s[NH];
    __shared__ float h1s[NH];
    h0s[lane] = 0.0f;
    h1s[lane] = 0.0f;

    const float* xb   = x   + (size_t)b*NT*NI;
    float*       outb = out + (size_t)b*NT*NO;

    // stage chunk 0 (in-wave ordering: write then read, no barrier)
    {
        float4 q0 = *(const float4*)(xb + lane*NI);
        float4 q1 = *(const float4*)(xb + lane*NI + 4);
        *(float4*)(xs + lane*NI)     = q0;
        *(float4*)(xs + lane*NI + 4) = q1;
    }

    float a0 = 0.f, a1 = 0.f, a2 = 0.f, a3 = 0.f;   // carry: Whh0 @ h0[t-1]

    for (int c = 0; c < NT/64; ++c) {
        // prefetch next x chunk into regs; LDS-write after last use of current
        float4 n0 = {0,0,0,0}, n1 = {0,0,0,0};
        if (c + 1 < NT/64) {
            n0 = *(const float4*)(xb + (size_t)((c+1)*64 + lane)*NI);
            n1 = *(const float4*)(xb + (size_t)((c+1)*64 + lane)*NI + 4);
        }

        #pragma unroll 1
        for (int tt = 0; tt < 64; ++tt) {
            const int t = c*64 + tt;

            // ---- phase 1: finish layer 0 for step t ----
            float4 xv0 = *(const float4*)(xs + tt*NI);
            float4 xv1 = *(const float4*)(xs + tt*NI + 4);
            float s00 = fmaf(xv0.x, wih0[0], a0 + bias0);
            float s01 = fmaf(xv0.y, wih0[1], a1);
            float s02 = fmaf(xv0.z, wih0[2], a2);
            float s03 = fmaf(xv0.w, wih0[3], a3);
            s00 = fmaf(xv1.x, wih0[4], s00);
            s01 = fmaf(xv1.y, wih0[5], s01);
            s02 = fmaf(xv1.z, wih0[6], s02);
            s03 = fmaf(xv1.w, wih0[7], s03);
            float h0n = tanh_fast((s00 + s01) + (s02 + s03));
            h0s[lane] = h0n;

            // ---- phase 2: Whh1 @ h1[t-1] (independent of h0n) + FC(t-1) ----
            float c0 = bias1, c1 = 0.f, c2 = 0.f, c3 = 0.f;
            #pragma unroll
            for (int k = 0; k < NH; k += 4) {
                float4 v = *(const float4*)(h1s + k);       // broadcast
                c0 = fmaf(v.x, whh1[k+0], c0);
                c1 = fmaf(v.y, whh1[k+1], c1);
                c2 = fmaf(v.z, whh1[k+2], c2);
                c3 = fmaf(v.w, whh1[k+3], c3);
            }
            float4 u0 = *(const float4*)(h1s + kg*8);       // per-lane FC slice
            float4 u1 = *(const float4*)(h1s + kg*8 + 4);
            float p = u0.x*wfc[0] + u0.y*wfc[1] + u0.z*wfc[2] + u0.w*wfc[3]
                    + u1.x*wfc[4] + u1.y*wfc[5] + u1.z*wfc[6] + u1.w*wfc[7];
            p += __shfl_xor(p, 8);
            p += __shfl_xor(p, 16);
            p += __shfl_xor(p, 32);
            if (t > 0 && lane < 8) outb[(size_t)(t-1)*NO + o] = p + bfc;

            // ---- phase 3: bcast h0[t]; Wih1 dot (this step) + Whh0 dot (next carry) ----
            float na0 = 0.f, na1 = 0.f, na2 = 0.f, na3 = 0.f;
            #pragma unroll
            for (int k = 0; k < NH; k += 4) {
                float4 v = *(const float4*)(h0s + k);       // broadcast (h0[t])
                c0  = fmaf(v.x, wih1[k+0], c0);
                c1  = fmaf(v.y, wih1[k+1], c1);
                c2  = fmaf(v.z, wih1[k+2], c2);
                c3  = fmaf(v.w, wih1[k+3], c3);
                na0 = fmaf(v.x, whh0[k+0], na0);
                na1 = fmaf(v.y, whh0[k+1], na1);
                na2 = fmaf(v.z, whh0[k+2], na2);
                na3 = fmaf(v.w, whh0[k+3], na3);
            }

            // ---- phase 4: layer-1 activation ----
            float h1n = tanh_fast((c0 + c1) + (c2 + c3));
            h1s[lane] = h1n;
            a0 = na0; a1 = na1; a2 = na2; a3 = na3;
        }

        if (c + 1 < NT/64) {
            *(float4*)(xs + lane*NI)     = n0;
            *(float4*)(xs + lane*NI + 4) = n1;
        }
    }

    // ---- final FC for t = NT-1 (h1s holds h1[NT-1]) ----
    {
        float4 u0 = *(const float4*)(h1s + kg*8);
        float4 u1 = *(const float4*)(h1s + kg*8 + 4);
        float p = u0.x*wfc[0] + u0.y*wfc[1] + u0.z*wfc[2] + u0.w*wfc[3]
                + u1.x*wfc[4] + u1.y*wfc[5] + u1.z*wfc[6] + u1.w*wfc[7];
        p += __shfl_xor(p, 8);
        p += __shfl_xor(p, 16);
        p += __shfl_xor(p, 32);
        if (lane < 8) outb[(size_t)(NT-1)*NO + o] = p + bfc;
    }

    // ---- hidden state: [2, B, H] appended after out ----
    const size_t hid_base = (size_t)NB*NT*NO;
    out[hid_base + (size_t)b*NH + lane]                  = h0s[lane];   // h0[NT-1]
    out[hid_base + (size_t)NB*NH + (size_t)b*NH + lane]  = h1s[lane];   // h1[NT-1]
}

extern "C" void kernel_launch(void* const* d_in, const int* in_sizes, int n_in,
                              void* d_out, int out_size, void* d_ws, size_t ws_size,
                              hipStream_t stream) {
    const float* x     = (const float*)d_in[0];
    const float* W_ih0 = (const float*)d_in[1];
    const float* W_hh0 = (const float*)d_in[2];
    const float* b_ih0 = (const float*)d_in[3];
    const float* b_hh0 = (const float*)d_in[4];
    const float* W_ih1 = (const float*)d_in[5];
    const float* W_hh1 = (const float*)d_in[6];
    const float* b_ih1 = (const float*)d_in[7];
    const float* b_hh1 = (const float*)d_in[8];
    const float* W_fc  = (const float*)d_in[9];
    const float* b_fc  = (const float*)d_in[10];

    rnn_wave<<<dim3(NB), dim3(64), 0, stream>>>(
        x, W_ih0, W_hh0, b_ih0, b_hh0,
        W_ih1, W_hh1, b_ih1, b_hh1, W_fc, b_fc,
        (float*)d_out);
}

// Round 4
// 1379.623 us; speedup vs baseline: 1.0514x; 1.0514x over previous
//
#include <hip/hip_runtime.h>

#define NI 8
#define NH 64
#define NO 8
#define NB 256
#define NT 2048
#define NCHUNK (NT / 64)   // 32 chunks of 64 timesteps

// tanh(s) = 1 - 2/(exp(2s)+1); safe at +-inf
__device__ __forceinline__ float tanh_fast(float s) {
    float e = __expf(2.0f * s);
    return fmaf(-2.0f, __builtin_amdgcn_rcpf(e + 1.0f), 1.0f);
}

// LDS-only barrier: drains ds ops (lgkmcnt) but NOT global loads/stores
// (vmcnt). HIP __syncthreads drains vmcnt(0) too, which stalls every step on
// FC-store / x-prefetch retirement — that was the round-2/3 floor.
__device__ __forceinline__ void barrier_lds() {
    asm volatile("s_waitcnt lgkmcnt(0)\n\ts_barrier" ::: "memory");
}

// 4-wave pipeline, one block per batch element.
//   wave0: h0[n]      = tanh(x[n]@Wih0^T + b0 + h0[n-1]@Whh0^T)        (n in [0,NT-1])
//   wave1: pih[n-1]   = h0[n-1]@Wih1^T + b1                             (n in [1,NT])
//   wave2: h1[n-2]    = tanh(pih[n-2] + h1[n-3]@Whh1^T)                 (n in [2,NT+1])
//   wave3: out[n-3]   = h1[n-3]@Wfc^T + bfc ; x-chunk staging           (n in [3,NT+2])
// All reads from buf[p], all writes to buf[p^1], p = n&1; ONE lds-barrier/step.
__global__ void __launch_bounds__(256, 1) rnn_pipe(
    const float* __restrict__ x,
    const float* __restrict__ W_ih0, const float* __restrict__ W_hh0,
    const float* __restrict__ b_ih0, const float* __restrict__ b_hh0,
    const float* __restrict__ W_ih1, const float* __restrict__ W_hh1,
    const float* __restrict__ b_ih1, const float* __restrict__ b_hh1,
    const float* __restrict__ W_fc,  const float* __restrict__ b_fc,
    float* __restrict__ out)
{
    const int b    = blockIdx.x;
    const int tid  = threadIdx.x;
    const int wid  = tid >> 6;
    const int lane = tid & 63;

    __shared__ float xs[2][64][NI];      // double-buffered x chunks
    __shared__ float h0buf[2][NH];
    __shared__ float h1buf[2][NH];
    __shared__ float pibuf[2][NH];

    // zero-init state buffers (both parities)
    if (tid < 2 * NH) {
        ((float*)h0buf)[tid] = 0.0f;
        ((float*)h1buf)[tid] = 0.0f;
        ((float*)pibuf)[tid] = 0.0f;
    }

    // ---- per-wave weights (each wave's live set <= ~80 regs -> no spill) ----
    float wrow[NH];   // whh0 / wih1 / whh1 depending on wave
    float wsm[8];     // wih0 (wave0) or wfc (wave3)
    float bias = 0.0f;

    if (wid == 0) {
        #pragma unroll
        for (int k = 0; k < NH; ++k) wrow[k] = W_hh0[lane * NH + k];
        #pragma unroll
        for (int i = 0; i < NI; ++i) wsm[i] = W_ih0[lane * NI + i];
        bias = b_ih0[lane] + b_hh0[lane];
    } else if (wid == 1) {
        #pragma unroll
        for (int k = 0; k < NH; ++k) wrow[k] = W_ih1[lane * NH + k];
        bias = b_ih1[lane] + b_hh1[lane];
    } else if (wid == 2) {
        #pragma unroll
        for (int k = 0; k < NH; ++k) wrow[k] = W_hh1[lane * NH + k];
    } else {
        const int o  = lane & 7;
        const int kg = lane >> 3;
        #pragma unroll
        for (int m = 0; m < 8; ++m) wsm[m] = W_fc[o * NH + kg * 8 + m];
        bias = b_fc[o];
    }

    const float* xb   = x   + (size_t)b * NT * NI;
    float*       outb = out + (size_t)b * NT * NO;

    // ---- prologue: wave3 stages chunk 0 ----
    if (wid == 3) {
        float4 a0 = *(const float4*)(xb + (size_t)lane * NI);
        float4 a1 = *(const float4*)(xb + (size_t)lane * NI + 4);
        *(float4*)(&xs[0][lane][0]) = a0;
        *(float4*)(&xs[0][lane][4]) = a1;
    }
    __syncthreads();   // once, before the loop — full sync is fine here

    float h_keep = 0.0f;             // wave0: h0[NT-1]; wave2: h1[NT-1]
    float4 pend0 = {0, 0, 0, 0}, pend1 = {0, 0, 0, 0};   // wave3 staging regs
    int p = 0;

    for (int n = 0; n < NT + 3; ++n) {
        if (wid == 0) {
            if (n < NT) {
                float a0 = bias, a1 = 0.f, a2 = 0.f, a3 = 0.f;
                #pragma unroll
                for (int k = 0; k < NH; k += 4) {
                    float4 v = *(const float4*)(&h0buf[p][k]);   // broadcast
                    a0 = fmaf(v.x, wrow[k + 0], a0);
                    a1 = fmaf(v.y, wrow[k + 1], a1);
                    a2 = fmaf(v.z, wrow[k + 2], a2);
                    a3 = fmaf(v.w, wrow[k + 3], a3);
                }
                const int tt = n & 63, cb = (n >> 6) & 1;
                float4 x0 = *(const float4*)(&xs[cb][tt][0]);
                float4 x1 = *(const float4*)(&xs[cb][tt][4]);
                a0 = fmaf(x0.x, wsm[0], a0); a1 = fmaf(x0.y, wsm[1], a1);
                a2 = fmaf(x0.z, wsm[2], a2); a3 = fmaf(x0.w, wsm[3], a3);
                a0 = fmaf(x1.x, wsm[4], a0); a1 = fmaf(x1.y, wsm[5], a1);
                a2 = fmaf(x1.z, wsm[6], a2); a3 = fmaf(x1.w, wsm[7], a3);
                float h0n = tanh_fast((a0 + a1) + (a2 + a3));
                h0buf[p ^ 1][lane] = h0n;
                h_keep = h0n;
            }
        } else if (wid == 1) {
            if (n >= 1 && n <= NT) {
                float a0 = bias, a1 = 0.f, a2 = 0.f, a3 = 0.f;
                #pragma unroll
                for (int k = 0; k < NH; k += 4) {
                    float4 v = *(const float4*)(&h0buf[p][k]);   // broadcast
                    a0 = fmaf(v.x, wrow[k + 0], a0);
                    a1 = fmaf(v.y, wrow[k + 1], a1);
                    a2 = fmaf(v.z, wrow[k + 2], a2);
                    a3 = fmaf(v.w, wrow[k + 3], a3);
                }
                pibuf[p ^ 1][lane] = (a0 + a1) + (a2 + a3);
            }
        } else if (wid == 2) {
            if (n >= 2 && n <= NT + 1) {
                float a0 = pibuf[p][lane], a1 = 0.f, a2 = 0.f, a3 = 0.f;
                #pragma unroll
                for (int k = 0; k < NH; k += 4) {
                    float4 v = *(const float4*)(&h1buf[p][k]);   // broadcast
                    a0 = fmaf(v.x, wrow[k + 0], a0);
                    a1 = fmaf(v.y, wrow[k + 1], a1);
                    a2 = fmaf(v.z, wrow[k + 2], a2);
                    a3 = fmaf(v.w, wrow[k + 3], a3);
                }
                float h1n = tanh_fast((a0 + a1) + (a2 + a3));
                h1buf[p ^ 1][lane] = h1n;
                h_keep = h1n;
            }
        } else {
            // ---- FC for step n-3 (global store: left in flight, never drained) ----
            if (n >= 3) {
                const int o  = lane & 7;
                const int kg = lane >> 3;
                float4 u0 = *(const float4*)(&h1buf[p][kg * 8]);
                float4 u1 = *(const float4*)(&h1buf[p][kg * 8 + 4]);
                float s = u0.x * wsm[0] + u0.y * wsm[1] + u0.z * wsm[2] + u0.w * wsm[3]
                        + u1.x * wsm[4] + u1.y * wsm[5] + u1.z * wsm[6] + u1.w * wsm[7];
                s += __shfl_xor(s, 8);
                s += __shfl_xor(s, 16);
                s += __shfl_xor(s, 32);
                if (lane < 8) outb[(size_t)(n - 3) * NO + o] = s + bias;
            }
            // ---- x staging: issue loads at m==0, LDS-write at m==16 ----
            const int m = n & 63;
            if (m == 0) {
                const int c = (n >> 6) + 1;
                if (c < NCHUNK) {
                    pend0 = *(const float4*)(xb + (size_t)(c * 64 + lane) * NI);
                    pend1 = *(const float4*)(xb + (size_t)(c * 64 + lane) * NI + 4);
                }
            } else if (m == 16) {
                const int c = (n >> 6) + 1;
                if (c < NCHUNK) {
                    *(float4*)(&xs[c & 1][lane][0]) = pend0;
                    *(float4*)(&xs[c & 1][lane][4]) = pend1;
                }
            }
        }
        barrier_lds();   // LDS-only: no vmcnt drain
        p ^= 1;
    }

    // ---- hidden state epilogue: [2, B, H] after out ----
    const size_t hid_base = (size_t)NB * NT * NO;
    if (wid == 0) out[hid_base + (size_t)b * NH + lane] = h_keep;                    // h0[NT-1]
    if (wid == 2) out[hid_base + (size_t)NB * NH + (size_t)b * NH + lane] = h_keep;  // h1[NT-1]
}

extern "C" void kernel_launch(void* const* d_in, const int* in_sizes, int n_in,
                              void* d_out, int out_size, void* d_ws, size_t ws_size,
                              hipStream_t stream) {
    const float* x     = (const float*)d_in[0];
    const float* W_ih0 = (const float*)d_in[1];
    const float* W_hh0 = (const float*)d_in[2];
    const float* b_ih0 = (const float*)d_in[3];
    const float* b_hh0 = (const float*)d_in[4];
    const float* W_ih1 = (const float*)d_in[5];
    const float* W_hh1 = (const float*)d_in[6];
    const float* b_ih1 = (const float*)d_in[7];
    const float* b_hh1 = (const float*)d_in[8];
    const float* W_fc  = (const float*)d_in[9];
    const float* b_fc  = (const float*)d_in[10];

    rnn_pipe<<<dim3(NB), dim3(256), 0, stream>>>(
        x, W_ih0, W_hh0, b_ih0, b_hh0,
        W_ih1, W_hh1, b_ih1, b_hh1, W_fc, b_fc,
        (float*)d_out);
}

// Round 5
// 1214.286 us; speedup vs baseline: 1.1945x; 1.1362x over previous
//
#include <hip/hip_runtime.h>

#define NI 8
#define NH 64
#define NO 8
#define NB 256
#define NT 2048
#define PIBUF 16   // pi ring depth (steps)

// tanh(s) = 1 - 2/(exp(2s)+1); safe at +-inf
__device__ __forceinline__ float tanh_fast(float s) {
    float e = __expf(2.0f * s);
    return fmaf(-2.0f, __builtin_amdgcn_rcpf(e + 1.0f), 1.0f);
}

// broadcast lane k's value to all lanes via v_readlane (VALU pipe, no LDS)
__device__ __forceinline__ float rlane(float v, int k) {
    return __int_as_float(__builtin_amdgcn_readlane(__float_as_int(v), k));
}

// 2 waves per block, one block per batch element, ZERO barriers in the loop.
//   wave A: h0[t] = tanh(Whh0@h0[t-1] + Wih0@x[t] + b0); pi[t] = Wih1@h0[t] -> LDS ring
//   wave B: h1[t] = tanh(pi[t] + b1 + Whh1@h1[t-1]); FC + out-store
// All matrix-vector broadcasts via v_readlane (register -> SGPR), NOT LDS.
// A->B sync: a_flag (A publishes, every 4 steps, after lgkmcnt(0)).
// B->A backpressure: b_flag (B publishes every 8 steps; A checks every 8).
__global__ void __launch_bounds__(128, 1) rnn_duo(
    const float* __restrict__ x,
    const float* __restrict__ W_ih0, const float* __restrict__ W_hh0,
    const float* __restrict__ b_ih0, const float* __restrict__ b_hh0,
    const float* __restrict__ W_ih1, const float* __restrict__ W_hh1,
    const float* __restrict__ b_ih1, const float* __restrict__ b_hh1,
    const float* __restrict__ W_fc,  const float* __restrict__ b_fc,
    float* __restrict__ out)
{
    const int b    = blockIdx.x;
    const int tid  = threadIdx.x;
    const int wid  = tid >> 6;
    const int lane = tid & 63;

    __shared__ float pi[PIBUF][NH];   // A -> B: wih1 @ h0[t] (raw, bias added on B)
    __shared__ float h1s[NH];         // B-local FC slice buffer
    __shared__ int   a_flag;          // highest t with pi[t] published
    __shared__ int   b_flag;          // highest t consumed by B

    if (tid == 0) { a_flag = -1; b_flag = -1; }
    __syncthreads();                  // once, before the loop

    volatile int* vaf = &a_flag;
    volatile int* vbf = &b_flag;

    const float*  xb   = x   + (size_t)b * NT * NI;
    float*        outb = out + (size_t)b * NT * NO;
    const size_t  hid  = (size_t)NB * NT * NO;

    if (wid == 0) {
        // ================= wave A: layer-0 chain =================
        float whh0[NH], wih1[NH], wih0[NI];
        #pragma unroll
        for (int k = 0; k < NH; ++k) whh0[k] = W_hh0[lane * NH + k];
        #pragma unroll
        for (int k = 0; k < NH; ++k) wih1[k] = W_ih1[lane * NH + k];
        #pragma unroll
        for (int i = 0; i < NI; ++i) wih0[i] = W_ih0[lane * NI + i];
        const float bias0 = b_ih0[lane] + b_hh0[lane];

        // x chunk in registers: lane j holds x[tc + j][0..8); rl by (t & 63)
        float4 xc0 = *(const float4*)(xb + (size_t)lane * NI);
        float4 xc1 = *(const float4*)(xb + (size_t)lane * NI + 4);
        float4 xn0 = xc0, xn1 = xc1;

        float h0n = 0.0f;   // h0[t-1]

        for (int t = 0; t < NT; ++t) {
            const int j = t & 63;
            if (j == 0) {
                if (t) { xc0 = xn0; xc1 = xn1; }
                const int c = (t >> 6) + 1;
                if (c < NT / 64) {   // prefetch next chunk (used 64 steps later)
                    xn0 = *(const float4*)(xb + (size_t)(c * 64 + lane) * NI);
                    xn1 = *(const float4*)(xb + (size_t)(c * 64 + lane) * NI + 4);
                }
            }
            // backpressure: about to write pi steps [t-1, t+6] -> overwrites
            // slots of steps [t-17, t-10]; need B consumed through t-10.
            if ((t & 7) == 0) {
                while (*vbf < t - 10) __builtin_amdgcn_s_sleep(1);
            }

            // x[t] dot (independent of recurrence)
            float xd;
            xd = rlane(xc0.x, j) * wih0[0];
            xd = fmaf(rlane(xc0.y, j), wih0[1], xd);
            xd = fmaf(rlane(xc0.z, j), wih0[2], xd);
            xd = fmaf(rlane(xc0.w, j), wih0[3], xd);
            xd = fmaf(rlane(xc1.x, j), wih0[4], xd);
            xd = fmaf(rlane(xc1.y, j), wih0[5], xd);
            xd = fmaf(rlane(xc1.z, j), wih0[6], xd);
            xd = fmaf(rlane(xc1.w, j), wih0[7], xd);

            // one readlane set over h0[t-1] feeds BOTH dots
            float c0 = bias0, c1 = 0.f, c2 = 0.f, c3 = 0.f;   // Whh0 carry
            float p0 = 0.f,   p1 = 0.f, p2 = 0.f, p3 = 0.f;   // Wih1 (pi[t-1])
            #pragma unroll
            for (int k = 0; k < NH; k += 4) {
                float s0 = rlane(h0n, k + 0);
                float s1 = rlane(h0n, k + 1);
                float s2 = rlane(h0n, k + 2);
                float s3 = rlane(h0n, k + 3);
                c0 = fmaf(s0, whh0[k + 0], c0);  p0 = fmaf(s0, wih1[k + 0], p0);
                c1 = fmaf(s1, whh0[k + 1], c1);  p1 = fmaf(s1, wih1[k + 1], p1);
                c2 = fmaf(s2, whh0[k + 2], c2);  p2 = fmaf(s2, wih1[k + 2], p2);
                c3 = fmaf(s3, whh0[k + 3], c3);  p3 = fmaf(s3, wih1[k + 3], p3);
            }
            if (t > 0) {
                pi[(t - 1) & (PIBUF - 1)][lane] = (p0 + p1) + (p2 + p3);
                if (((t - 1) & 3) == 3) {
                    asm volatile("s_waitcnt lgkmcnt(0)" ::: "memory");
                    *vaf = t - 1;
                }
            }
            h0n = tanh_fast(((c0 + c1) + (c2 + c3)) + xd);
        }

        // epilogue: pi for t = NT-1 (h0n = h0[NT-1])
        {
            float p0 = 0.f, p1 = 0.f, p2 = 0.f, p3 = 0.f;
            #pragma unroll
            for (int k = 0; k < NH; k += 4) {
                float s0 = rlane(h0n, k + 0);
                float s1 = rlane(h0n, k + 1);
                float s2 = rlane(h0n, k + 2);
                float s3 = rlane(h0n, k + 3);
                p0 = fmaf(s0, wih1[k + 0], p0);
                p1 = fmaf(s1, wih1[k + 1], p1);
                p2 = fmaf(s2, wih1[k + 2], p2);
                p3 = fmaf(s3, wih1[k + 3], p3);
            }
            pi[(NT - 1) & (PIBUF - 1)][lane] = (p0 + p1) + (p2 + p3);
            asm volatile("s_waitcnt lgkmcnt(0)" ::: "memory");
            *vaf = NT - 1;
        }
        out[hid + (size_t)b * NH + lane] = h0n;                       // h0 final
    } else {
        // ================= wave B: layer-1 chain + FC =================
        float whh1[NH];
        #pragma unroll
        for (int k = 0; k < NH; ++k) whh1[k] = W_hh1[lane * NH + k];
        const float bias1 = b_ih1[lane] + b_hh1[lane];

        const int o  = lane & 7;
        const int kg = lane >> 3;
        float wfc[8];
        #pragma unroll
        for (int m = 0; m < 8; ++m) wfc[m] = W_fc[o * NH + kg * 8 + m];
        const float bfc = b_fc[o];

        float h1p = 0.0f;   // h1[t-1]

        for (int t = 0; t < NT; ++t) {
            while (*vaf < t) __builtin_amdgcn_s_sleep(1);
            asm volatile("" ::: "memory");        // don't hoist pi read above poll
            const float pv = pi[t & (PIBUF - 1)][lane];

            float c0 = bias1 + pv, c1 = 0.f, c2 = 0.f, c3 = 0.f;
            #pragma unroll
            for (int k = 0; k < NH; k += 4) {
                float s0 = rlane(h1p, k + 0);
                float s1 = rlane(h1p, k + 1);
                float s2 = rlane(h1p, k + 2);
                float s3 = rlane(h1p, k + 3);
                c0 = fmaf(s0, whh1[k + 0], c0);
                c1 = fmaf(s1, whh1[k + 1], c1);
                c2 = fmaf(s2, whh1[k + 2], c2);
                c3 = fmaf(s3, whh1[k + 3], c3);
            }
            const float h1n = tanh_fast((c0 + c1) + (c2 + c3));

            // FC: publish h1n to B-local LDS, read own slice (same-wave, in-order)
            h1s[lane] = h1n;
            float4 u0 = *(const float4*)(&h1s[kg * 8]);
            float4 u1 = *(const float4*)(&h1s[kg * 8 + 4]);
            float p = u0.x * wfc[0] + u0.y * wfc[1] + u0.z * wfc[2] + u0.w * wfc[3]
                    + u1.x * wfc[4] + u1.y * wfc[5] + u1.z * wfc[6] + u1.w * wfc[7];
            p += __shfl_xor(p, 8);
            p += __shfl_xor(p, 16);
            p += __shfl_xor(p, 32);
            if (lane < NO) outb[(size_t)t * NO + o] = p + bfc;   // fire-and-forget

            if ((t & 7) == 7) *vbf = t;
            h1p = h1n;
        }
        out[hid + (size_t)NB * NH + (size_t)b * NH + lane] = h1p;     // h1 final
    }
}

extern "C" void kernel_launch(void* const* d_in, const int* in_sizes, int n_in,
                              void* d_out, int out_size, void* d_ws, size_t ws_size,
                              hipStream_t stream) {
    const float* x     = (const float*)d_in[0];
    const float* W_ih0 = (const float*)d_in[1];
    const float* W_hh0 = (const float*)d_in[2];
    const float* b_ih0 = (const float*)d_in[3];
    const float* b_hh0 = (const float*)d_in[4];
    const float* W_ih1 = (const float*)d_in[5];
    const float* W_hh1 = (const float*)d_in[6];
    const float* b_ih1 = (const float*)d_in[7];
    const float* b_hh1 = (const float*)d_in[8];
    const float* W_fc  = (const float*)d_in[9];
    const float* b_fc  = (const float*)d_in[10];

    rnn_duo<<<dim3(NB), dim3(128), 0, stream>>>(
        x, W_ih0, W_hh0, b_ih0, b_hh0,
        W_ih1, W_hh1, b_ih1, b_hh1, W_fc, b_fc,
        (float*)d_out);
}

// Round 6
// 1059.479 us; speedup vs baseline: 1.3691x; 1.1461x over previous
//
#include <hip/hip_runtime.h>

#define NI 8
#define NH 64
#define NO 8
#define NB 256
#define NT 2048
#define RING 16

// tanh(s) = 1 - 2/(exp(2s)+1); safe at +-inf
__device__ __forceinline__ float tanh_fast(float s) {
    float e = __expf(2.0f * s);
    return fmaf(-2.0f, __builtin_amdgcn_rcpf(e + 1.0f), 1.0f);
}

// broadcast lane k's value to all lanes via v_readlane (VALU, no LDS pipe)
__device__ __forceinline__ float rlane(float v, int k) {
    return __int_as_float(__builtin_amdgcn_readlane(__float_as_int(v), k));
}

// 3 waves per block, one block per batch element, ZERO barriers in the loop.
// Every wave's live register set < 110 VGPRs -> no AGPR banking (the R1/R3/R5
// 2x VALU bloat: compiler caps arch VGPRs ~124 and shuttles overflow weights
// through AGPRs on the serial chain).
//   wave A: h0[t] = tanh(Whh0@h0[t-1] + Wih0@x[t] + b0)      -> h0 ring
//   wave B: pi[t] = Wih1@h0[t]                                -> pi ring
//   wave C: h1[t] = tanh(pi[t] + b1 + Whh1@h1[t-1]); FC + store
// Flags: af/bf (availability, publish gran 2 after lgkmcnt(0)),
//        cf/bf (backpressure, check gran 8, margin 9 < RING).
__global__ void __launch_bounds__(192, 1) rnn_tri(
    const float* __restrict__ x,
    const float* __restrict__ W_ih0, const float* __restrict__ W_hh0,
    const float* __restrict__ b_ih0, const float* __restrict__ b_hh0,
    const float* __restrict__ W_ih1, const float* __restrict__ W_hh1,
    const float* __restrict__ b_ih1, const float* __restrict__ b_hh1,
    const float* __restrict__ W_fc,  const float* __restrict__ b_fc,
    float* __restrict__ out)
{
    const int b    = blockIdx.x;
    const int tid  = threadIdx.x;
    const int wid  = tid >> 6;
    const int lane = tid & 63;

    __shared__ float xs[2][64][NI];     // double-buffered x chunks
    __shared__ float h0r[RING][NH];     // A -> B: h0[t] ring
    __shared__ float pir[RING][NH];     // B -> C: Wih1@h0[t] ring
    __shared__ float h1s[NH];           // C-local FC slice buffer
    __shared__ int   af, bfl, cfl;

    if (tid == 0) { af = -1; bfl = -1; cfl = -1; }
    __syncthreads();                    // once, before the loop

    volatile int* vaf = &af;
    volatile int* vbf = &bfl;
    volatile int* vcf = &cfl;

    const float*  xb   = x   + (size_t)b * NT * NI;
    float*        outb = out + (size_t)b * NT * NO;
    const size_t  hid  = (size_t)NB * NT * NO;

    if (wid == 0) {
        // ================= wave A: layer-0 chain =================
        float whh0[NH], wih0[NI];
        #pragma unroll
        for (int k = 0; k < NH; ++k) whh0[k] = W_hh0[lane * NH + k];
        #pragma unroll
        for (int i = 0; i < NI; ++i) wih0[i] = W_ih0[lane * NI + i];
        const float bias0 = b_ih0[lane] + b_hh0[lane];

        // stage x chunk 0 (same-wave write->read, in-order)
        {
            float4 q0 = *(const float4*)(xb + (size_t)lane * NI);
            float4 q1 = *(const float4*)(xb + (size_t)lane * NI + 4);
            *(float4*)(&xs[0][lane][0]) = q0;
            *(float4*)(&xs[0][lane][4]) = q1;
        }
        float4 xn0 = {0,0,0,0}, xn1 = {0,0,0,0};
        float h0n = 0.0f;

        for (int t = 0; t < NT; ++t) {
            const int j = t & 63;
            if (j == 0) {                       // prefetch next chunk (global)
                const int c = (t >> 6) + 1;
                if (c < NT / 64) {
                    xn0 = *(const float4*)(xb + (size_t)(c * 64 + lane) * NI);
                    xn1 = *(const float4*)(xb + (size_t)(c * 64 + lane) * NI + 4);
                }
            }
            if ((t & 7) == 0) {                 // ring backpressure vs B
                while (*vbf < t - 9) __builtin_amdgcn_s_sleep(1);
                asm volatile("" ::: "memory");
            }
            // x broadcast reads issued early; latency hides under the dot
            const float4 xv0 = *(const float4*)(&xs[(t >> 6) & 1][j][0]);
            const float4 xv1 = *(const float4*)(&xs[(t >> 6) & 1][j][4]);

            float c0 = bias0, c1 = 0.f, c2 = 0.f, c3 = 0.f;
            #pragma unroll
            for (int k = 0; k < NH; k += 8) {   // groups of 8: rl->fma distance 7+
                const float s0 = rlane(h0n, k + 0), s1 = rlane(h0n, k + 1);
                const float s2 = rlane(h0n, k + 2), s3 = rlane(h0n, k + 3);
                const float s4 = rlane(h0n, k + 4), s5 = rlane(h0n, k + 5);
                const float s6 = rlane(h0n, k + 6), s7 = rlane(h0n, k + 7);
                c0 = fmaf(s0, whh0[k + 0], c0); c1 = fmaf(s1, whh0[k + 1], c1);
                c2 = fmaf(s2, whh0[k + 2], c2); c3 = fmaf(s3, whh0[k + 3], c3);
                c0 = fmaf(s4, whh0[k + 4], c0); c1 = fmaf(s5, whh0[k + 5], c1);
                c2 = fmaf(s6, whh0[k + 6], c2); c3 = fmaf(s7, whh0[k + 7], c3);
            }
            c0 = fmaf(xv0.x, wih0[0], c0); c1 = fmaf(xv0.y, wih0[1], c1);
            c2 = fmaf(xv0.z, wih0[2], c2); c3 = fmaf(xv0.w, wih0[3], c3);
            c0 = fmaf(xv1.x, wih0[4], c0); c1 = fmaf(xv1.y, wih0[5], c1);
            c2 = fmaf(xv1.z, wih0[6], c2); c3 = fmaf(xv1.w, wih0[7], c3);
            h0n = tanh_fast((c0 + c1) + (c2 + c3));

            h0r[t & (RING - 1)][lane] = h0n;
            if (t & 1) {                        // publish gran 2
                asm volatile("s_waitcnt lgkmcnt(0)" ::: "memory");
                *vaf = t;
            }
            if (j == 48) {                      // LDS-write prefetched chunk
                const int c = (t >> 6) + 1;
                if (c < NT / 64) {
                    *(float4*)(&xs[c & 1][lane][0]) = xn0;
                    *(float4*)(&xs[c & 1][lane][4]) = xn1;
                }
            }
        }
        out[hid + (size_t)b * NH + lane] = h0n;                     // h0 final
    } else if (wid == 1) {
        // ================= wave B: pi producer =================
        float wih1[NH];
        #pragma unroll
        for (int k = 0; k < NH; ++k) wih1[k] = W_ih1[lane * NH + k];

        for (int t = 0; t < NT; ++t) {
            if ((t & 3) == 0) {                 // availability from A (gran 4)
                const int need = (t + 3 < NT) ? t + 3 : NT - 1;
                while (*vaf < need) __builtin_amdgcn_s_sleep(1);
                asm volatile("" ::: "memory");
            }
            if ((t & 7) == 0) {                 // ring backpressure vs C
                while (*vcf < t - 9) __builtin_amdgcn_s_sleep(1);
                asm volatile("" ::: "memory");
            }
            float p0 = 0.f, p1 = 0.f, p2 = 0.f, p3 = 0.f;
            #pragma unroll
            for (int k = 0; k < NH; k += 4) {
                const float4 v = *(const float4*)(&h0r[t & (RING - 1)][k]);  // bcast
                p0 = fmaf(v.x, wih1[k + 0], p0);
                p1 = fmaf(v.y, wih1[k + 1], p1);
                p2 = fmaf(v.z, wih1[k + 2], p2);
                p3 = fmaf(v.w, wih1[k + 3], p3);
            }
            pir[t & (RING - 1)][lane] = (p0 + p1) + (p2 + p3);
            if (t & 1) {                        // publish gran 2
                asm volatile("s_waitcnt lgkmcnt(0)" ::: "memory");
                *vbf = t;
            }
        }
    } else {
        // ================= wave C: layer-1 chain + FC =================
        float whh1[NH];
        #pragma unroll
        for (int k = 0; k < NH; ++k) whh1[k] = W_hh1[lane * NH + k];
        const float bias1 = b_ih1[lane] + b_hh1[lane];

        const int o  = lane & 7;
        const int kg = lane >> 3;
        float wfc[8];
        #pragma unroll
        for (int m = 0; m < 8; ++m) wfc[m] = W_fc[o * NH + kg * 8 + m];
        const float bfc = b_fc[o];

        float h1p = 0.0f;

        for (int t = 0; t < NT; ++t) {
            if ((t & 3) == 0) {                 // availability from B (gran 4)
                const int need = (t + 3 < NT) ? t + 3 : NT - 1;
                while (*vbf < need) __builtin_amdgcn_s_sleep(1);
                asm volatile("" ::: "memory");
            }
            const float pv = pir[t & (RING - 1)][lane];

            float c0 = bias1 + pv, c1 = 0.f, c2 = 0.f, c3 = 0.f;
            #pragma unroll
            for (int k = 0; k < NH; k += 8) {
                const float s0 = rlane(h1p, k + 0), s1 = rlane(h1p, k + 1);
                const float s2 = rlane(h1p, k + 2), s3 = rlane(h1p, k + 3);
                const float s4 = rlane(h1p, k + 4), s5 = rlane(h1p, k + 5);
                const float s6 = rlane(h1p, k + 6), s7 = rlane(h1p, k + 7);
                c0 = fmaf(s0, whh1[k + 0], c0); c1 = fmaf(s1, whh1[k + 1], c1);
                c2 = fmaf(s2, whh1[k + 2], c2); c3 = fmaf(s3, whh1[k + 3], c3);
                c0 = fmaf(s4, whh1[k + 4], c0); c1 = fmaf(s5, whh1[k + 5], c1);
                c2 = fmaf(s6, whh1[k + 6], c2); c3 = fmaf(s7, whh1[k + 7], c3);
            }
            const float h1n = tanh_fast((c0 + c1) + (c2 + c3));

            // FC: publish h1n, read own slice (same-wave, in-order)
            h1s[lane] = h1n;
            const float4 u0 = *(const float4*)(&h1s[kg * 8]);
            const float4 u1 = *(const float4*)(&h1s[kg * 8 + 4]);
            float p = u0.x * wfc[0] + u0.y * wfc[1] + u0.z * wfc[2] + u0.w * wfc[3]
                    + u1.x * wfc[4] + u1.y * wfc[5] + u1.z * wfc[6] + u1.w * wfc[7];
            p += __shfl_xor(p, 8);
            p += __shfl_xor(p, 16);
            p += __shfl_xor(p, 32);
            if (lane < NO) outb[(size_t)t * NO + o] = p + bfc;   // fire-and-forget

            if ((t & 3) == 3) {                 // progress for B's backpressure
                asm volatile("s_waitcnt lgkmcnt(0)" ::: "memory");
                *vcf = t;
            }
            h1p = h1n;
        }
        out[hid + (size_t)NB * NH + (size_t)b * NH + lane] = h1p;   // h1 final
    }
}

extern "C" void kernel_launch(void* const* d_in, const int* in_sizes, int n_in,
                              void* d_out, int out_size, void* d_ws, size_t ws_size,
                              hipStream_t stream) {
    const float* x     = (const float*)d_in[0];
    const float* W_ih0 = (const float*)d_in[1];
    const float* W_hh0 = (const float*)d_in[2];
    const float* b_ih0 = (const float*)d_in[3];
    const float* b_hh0 = (const float*)d_in[4];
    const float* W_ih1 = (const float*)d_in[5];
    const float* W_hh1 = (const float*)d_in[6];
    const float* b_ih1 = (const float*)d_in[7];
    const float* b_hh1 = (const float*)d_in[8];
    const float* W_fc  = (const float*)d_in[9];
    const float* b_fc  = (const float*)d_in[10];

    rnn_tri<<<dim3(NB), dim3(192), 0, stream>>>(
        x, W_ih0, W_hh0, b_ih0, b_hh0,
        W_ih1, W_hh1, b_ih1, b_hh1, W_fc, b_fc,
        (float*)d_out);
}

// Round 7
// 1054.426 us; speedup vs baseline: 1.3756x; 1.0048x over previous
//
#include <hip/hip_runtime.h>

#define NI 8
#define NH 64
#define NO 8
#define NB 256
#define NT 2048
#define RING 16

// tanh(s) = 1 - 2/(exp(2s)+1); safe at +-inf
__device__ __forceinline__ float tanh_fast(float s) {
    float e = __expf(2.0f * s);
    return fmaf(-2.0f, __builtin_amdgcn_rcpf(e + 1.0f), 1.0f);
}

// broadcast lane k's value to all lanes via v_readlane (VALU, no LDS pipe)
__device__ __forceinline__ float rlane(float v, int k) {
    return __int_as_float(__builtin_amdgcn_readlane(__float_as_int(v), k));
}

// R6 structure (3 waves, zero barriers, flag/ring handoff) with ONE register
// allocation change: wrow/wsm are declared ONCE at function scope and loaded
// via a role-selected pointer. R1/R3/R5/R6 declared per-role arrays; the
// allocator didn't coalesce them, capped arch VGPRs (60 in R6) and banked the
// weights in AGPRs -> v_accvgpr_read per use = 2x VALU on the serial chain.
// R2 (single shared array, VGPR=76) is the in-sample proof of this pattern.
//   wave A: h0[t] = tanh(Whh0@h0[t-1] + Wih0@x[t] + b0)      -> h0 ring
//   wave B: pi[t] = Wih1@h0[t]                                -> pi ring
//   wave C: h1[t] = tanh(pi[t] + b1 + Whh1@h1[t-1]); FC + store
__global__ void __launch_bounds__(192, 1) rnn_tri2(
    const float* __restrict__ x,
    const float* __restrict__ W_ih0, const float* __restrict__ W_hh0,
    const float* __restrict__ b_ih0, const float* __restrict__ b_hh0,
    const float* __restrict__ W_ih1, const float* __restrict__ W_hh1,
    const float* __restrict__ b_ih1, const float* __restrict__ b_hh1,
    const float* __restrict__ W_fc,  const float* __restrict__ b_fc,
    float* __restrict__ out)
{
    const int b    = blockIdx.x;
    const int tid  = threadIdx.x;
    const int wid  = tid >> 6;
    const int lane = tid & 63;
    const int o    = lane & 7;
    const int kg   = lane >> 3;

    __shared__ float xs[2][64][NI];     // double-buffered x chunks (wave A)
    __shared__ float h0r[RING][NH];     // A -> B: h0[t] ring
    __shared__ float pir[RING][NH];     // B -> C: Wih1@h0[t] ring
    __shared__ float h1s[NH];           // C-local FC slice buffer
    __shared__ int   af, bfl, cfl;

    if (tid == 0) { af = -1; bfl = -1; cfl = -1; }

    // ---- SINGLE shared register arrays, role-selected source pointers ----
    float wrow[NH];
    const float* wsrc = (wid == 0) ? (W_hh0 + lane * NH)
                      : (wid == 1) ? (W_ih1 + lane * NH)
                                   : (W_hh1 + lane * NH);
    #pragma unroll
    for (int k = 0; k < NH; ++k) wrow[k] = wsrc[k];

    float wsm[8];
    const float* ssrc = (wid == 2) ? (W_fc + o * NH + kg * 8)
                                   : (W_ih0 + lane * NI);
    #pragma unroll
    for (int m = 0; m < 8; ++m) wsm[m] = ssrc[m];

    const float bias  = (wid == 0) ? (b_ih0[lane] + b_hh0[lane])
                      : (wid == 2) ? (b_ih1[lane] + b_hh1[lane]) : 0.0f;
    const float bias2 = (wid == 2) ? b_fc[o] : 0.0f;

    __syncthreads();                    // once, before the loop

    volatile int* vaf = &af;
    volatile int* vbf = &bfl;
    volatile int* vcf = &cfl;

    const float*  xb   = x   + (size_t)b * NT * NI;
    float*        outb = out + (size_t)b * NT * NO;
    const size_t  hid  = (size_t)NB * NT * NO;

    if (wid == 0) {
        // ================= wave A: layer-0 chain =================
        // stage x chunk 0 (same-wave write->read, in-order)
        {
            float4 q0 = *(const float4*)(xb + (size_t)lane * NI);
            float4 q1 = *(const float4*)(xb + (size_t)lane * NI + 4);
            *(float4*)(&xs[0][lane][0]) = q0;
            *(float4*)(&xs[0][lane][4]) = q1;
        }
        float4 xn0 = {0,0,0,0}, xn1 = {0,0,0,0};
        float h0n = 0.0f;

        for (int t = 0; t < NT; ++t) {
            const int j = t & 63;
            if (j == 0) {                       // prefetch next chunk (global)
                const int c = (t >> 6) + 1;
                if (c < NT / 64) {
                    xn0 = *(const float4*)(xb + (size_t)(c * 64 + lane) * NI);
                    xn1 = *(const float4*)(xb + (size_t)(c * 64 + lane) * NI + 4);
                }
            }
            if ((t & 7) == 0) {                 // ring backpressure vs B
                while (*vbf < t - 9) __builtin_amdgcn_s_sleep(1);
                asm volatile("" ::: "memory");
            }
            // x broadcast reads issued early; latency hides under the dot
            const float4 xv0 = *(const float4*)(&xs[(t >> 6) & 1][j][0]);
            const float4 xv1 = *(const float4*)(&xs[(t >> 6) & 1][j][4]);

            float c0 = bias, c1 = 0.f, c2 = 0.f, c3 = 0.f;
            #pragma unroll
            for (int k = 0; k < NH; k += 8) {   // groups of 8: rl->fma distance
                const float s0 = rlane(h0n, k + 0), s1 = rlane(h0n, k + 1);
                const float s2 = rlane(h0n, k + 2), s3 = rlane(h0n, k + 3);
                const float s4 = rlane(h0n, k + 4), s5 = rlane(h0n, k + 5);
                const float s6 = rlane(h0n, k + 6), s7 = rlane(h0n, k + 7);
                c0 = fmaf(s0, wrow[k + 0], c0); c1 = fmaf(s1, wrow[k + 1], c1);
                c2 = fmaf(s2, wrow[k + 2], c2); c3 = fmaf(s3, wrow[k + 3], c3);
                c0 = fmaf(s4, wrow[k + 4], c0); c1 = fmaf(s5, wrow[k + 5], c1);
                c2 = fmaf(s6, wrow[k + 6], c2); c3 = fmaf(s7, wrow[k + 7], c3);
            }
            c0 = fmaf(xv0.x, wsm[0], c0); c1 = fmaf(xv0.y, wsm[1], c1);
            c2 = fmaf(xv0.z, wsm[2], c2); c3 = fmaf(xv0.w, wsm[3], c3);
            c0 = fmaf(xv1.x, wsm[4], c0); c1 = fmaf(xv1.y, wsm[5], c1);
            c2 = fmaf(xv1.z, wsm[6], c2); c3 = fmaf(xv1.w, wsm[7], c3);
            h0n = tanh_fast((c0 + c1) + (c2 + c3));

            h0r[t & (RING - 1)][lane] = h0n;
            if (t & 1) {                        // publish gran 2
                asm volatile("s_waitcnt lgkmcnt(0)" ::: "memory");
                *vaf = t;
            }
            if (j == 48) {                      // LDS-write prefetched chunk
                const int c = (t >> 6) + 1;
                if (c < NT / 64) {
                    *(float4*)(&xs[c & 1][lane][0]) = xn0;
                    *(float4*)(&xs[c & 1][lane][4]) = xn1;
                }
            }
        }
        out[hid + (size_t)b * NH + lane] = h0n;                     // h0 final
    } else if (wid == 1) {
        // ================= wave B: pi producer =================
        for (int t = 0; t < NT; ++t) {
            if ((t & 3) == 0) {                 // availability from A (gran 4)
                const int need = (t + 3 < NT) ? t + 3 : NT - 1;
                while (*vaf < need) __builtin_amdgcn_s_sleep(1);
                asm volatile("" ::: "memory");
            }
            if ((t & 7) == 0) {                 // ring backpressure vs C
                while (*vcf < t - 9) __builtin_amdgcn_s_sleep(1);
                asm volatile("" ::: "memory");
            }
            float p0 = 0.f, p1 = 0.f, p2 = 0.f, p3 = 0.f;
            #pragma unroll
            for (int k = 0; k < NH; k += 4) {
                const float4 v = *(const float4*)(&h0r[t & (RING - 1)][k]);  // bcast
                p0 = fmaf(v.x, wrow[k + 0], p0);
                p1 = fmaf(v.y, wrow[k + 1], p1);
                p2 = fmaf(v.z, wrow[k + 2], p2);
                p3 = fmaf(v.w, wrow[k + 3], p3);
            }
            pir[t & (RING - 1)][lane] = (p0 + p1) + (p2 + p3);
            if (t & 1) {                        // publish gran 2
                asm volatile("s_waitcnt lgkmcnt(0)" ::: "memory");
                *vbf = t;
            }
        }
    } else {
        // ================= wave C: layer-1 chain + FC =================
        float h1p = 0.0f;

        for (int t = 0; t < NT; ++t) {
            if ((t & 3) == 0) {                 // availability from B (gran 4)
                const int need = (t + 3 < NT) ? t + 3 : NT - 1;
                while (*vbf < need) __builtin_amdgcn_s_sleep(1);
                asm volatile("" ::: "memory");
            }
            const float pv = pir[t & (RING - 1)][lane];

            float c0 = bias + pv, c1 = 0.f, c2 = 0.f, c3 = 0.f;
            #pragma unroll
            for (int k = 0; k < NH; k += 8) {
                const float s0 = rlane(h1p, k + 0), s1 = rlane(h1p, k + 1);
                const float s2 = rlane(h1p, k + 2), s3 = rlane(h1p, k + 3);
                const float s4 = rlane(h1p, k + 4), s5 = rlane(h1p, k + 5);
                const float s6 = rlane(h1p, k + 6), s7 = rlane(h1p, k + 7);
                c0 = fmaf(s0, wrow[k + 0], c0); c1 = fmaf(s1, wrow[k + 1], c1);
                c2 = fmaf(s2, wrow[k + 2], c2); c3 = fmaf(s3, wrow[k + 3], c3);
                c0 = fmaf(s4, wrow[k + 4], c0); c1 = fmaf(s5, wrow[k + 5], c1);
                c2 = fmaf(s6, wrow[k + 6], c2); c3 = fmaf(s7, wrow[k + 7], c3);
            }
            const float h1n = tanh_fast((c0 + c1) + (c2 + c3));

            // FC: publish h1n, read own slice (same-wave, in-order; off-chain)
            h1s[lane] = h1n;
            const float4 u0 = *(const float4*)(&h1s[kg * 8]);
            const float4 u1 = *(const float4*)(&h1s[kg * 8 + 4]);
            float p = u0.x * wsm[0] + u0.y * wsm[1] + u0.z * wsm[2] + u0.w * wsm[3]
                    + u1.x * wsm[4] + u1.y * wsm[5] + u1.z * wsm[6] + u1.w * wsm[7];
            p += __shfl_xor(p, 8);
            p += __shfl_xor(p, 16);
            p += __shfl_xor(p, 32);
            if (lane < NO) outb[(size_t)t * NO + o] = p + bias2;  // fire-and-forget

            if ((t & 3) == 3) {                 // progress for B's backpressure
                asm volatile("s_waitcnt lgkmcnt(0)" ::: "memory");
                *vcf = t;
            }
            h1p = h1n;
        }
        out[hid + (size_t)NB * NH + (size_t)b * NH + lane] = h1p;   // h1 final
    }
}

extern "C" void kernel_launch(void* const* d_in, const int* in_sizes, int n_in,
                              void* d_out, int out_size, void* d_ws, size_t ws_size,
                              hipStream_t stream) {
    const float* x     = (const float*)d_in[0];
    const float* W_ih0 = (const float*)d_in[1];
    const float* W_hh0 = (const float*)d_in[2];
    const float* b_ih0 = (const float*)d_in[3];
    const float* b_hh0 = (const float*)d_in[4];
    const float* W_ih1 = (const float*)d_in[5];
    const float* W_hh1 = (const float*)d_in[6];
    const float* b_ih1 = (const float*)d_in[7];
    const float* b_hh1 = (const float*)d_in[8];
    const float* W_fc  = (const float*)d_in[9];
    const float* b_fc  = (const float*)d_in[10];

    rnn_tri2<<<dim3(NB), dim3(192), 0, stream>>>(
        x, W_ih0, W_hh0, b_ih0, b_hh0,
        W_ih1, W_hh1, b_ih1, b_hh1, W_fc, b_fc,
        (float*)d_out);
}